// Round 5
// baseline (201.082 us; speedup 1.0000x reference)
//
#include <hip/hip_runtime.h>
#include <math.h>

// Fused single-kernel DSVF biquad IIR (scipy lfilter DF2T), B=512, T=32768.
// One block per row: 512 threads (8 waves), chunk = 64 samples per thread.
// R5 = R4 body (verified correct) + fixed occupancy attribute.
//   R3/R4 lesson: __launch_bounds__(512,4) made the backend target 8
//   waves/EU (64-VGPR budget) and spill c[16] (64 VGPRs) to SCRATCH ->
//   ~130-160 MB phantom HBM traffic (FETCH 136/WRITE 227 MB, VGPR_Count=64).
//   amdgpu_waves_per_eu(4,4) pins 4 waves/EU -> 128-VGPR budget (R2 proved
//   the body fits: VGPR_Count=128, FETCH 33/WRITE 68 MB), 16 waves/CU =
//   2 blocks/CU with the 40 KB LDS footprint -> all 512 blocks resident.
// Structure:
//   stage-in : coalesced global->LDS->per-lane chunks via 4 KB/wave buffer,
//              4 wave-synchronous rounds (s_waitcnt lgkmcnt(0), no barrier).
//              Lane l's chunk = slice i=l>>2 at lanes 16*(l&3)+k; round j
//              stages slices 4j..4j+3; XOR swizzle q^((q>>4)&7) for banks.
//   pass1    : zero-init chunk state; x held in c[16] registers.
//   scan     : f64 LDS Kogge-Stone over 512 chunks, P = M^64 (verified);
//              exclusive prefix s[t-1] = chunk's true entering state.
//   pass2    : rerun chunk from entering state; reverse transpose; store.
// HBM: read x once (67 MB, partly L3-resident) + write y once (67 MB).

namespace {
constexpr int kT = 32768;
constexpr int kThreads = 512;   // 8 waves, one block per row
}

__device__ inline void coeffs_f32(const float* g, const float* r,
                                  const float* mhp, const float* mbp,
                                  const float* mlp, float& b0, float& b1,
                                  float& b2, float& a1, float& a2) {
  float graw = g[0], rraw = r[0];
  float sig = 1.0f / (1.0f + expf(-graw));
  float gg = tanf(1.5707963267948966f * sig);            // tan(pi*sigmoid/2)
  float rr = (rraw > 20.0f) ? rraw : log1pf(expf(rraw)); // softplus
  float g2 = gg * gg;
  float m_hp = mhp[0], m_bp = mbp[0], m_lp = mlp[0];
  float B0 = g2 * m_lp + gg * m_bp + m_hp;
  float B1 = 2.0f * g2 * m_lp - 2.0f * m_hp;
  float B2 = g2 * m_lp - gg * m_bp + m_hp;
  float A0 = g2 + 2.0f * rr * gg + 1.0f;
  float A1 = 2.0f * g2 - 2.0f;
  float A2 = g2 - 2.0f * rr * gg + 1.0f;
  float inv = 1.0f / A0;
  b0 = B0 * inv; b1 = B1 * inv; b2 = B2 * inv;
  a1 = A1 * inv; a2 = A2 * inv;
}

#define IIR_STEP(xx, yy)                                         \
  do {                                                           \
    yy = fmaf(b0, xx, z1);                                       \
    z1 = fmaf(na1, yy, fmaf(b1, xx, z2));                        \
    z2 = fmaf(na2, yy, b2 * xx);                                 \
  } while (0)

#define MAT_SQ(w00, w01, w10, w11)                               \
  do {                                                           \
    double t00 = w00 * w00 + w01 * w10;                          \
    double t01 = w00 * w01 + w01 * w11;                          \
    double t10 = w10 * w00 + w11 * w10;                          \
    double t11 = w10 * w01 + w11 * w11;                          \
    w00 = t00; w01 = t01; w10 = t10; w11 = t11;                  \
  } while (0)

#define LGKM0() asm volatile("s_waitcnt lgkmcnt(0)" ::: "memory")

__device__ __forceinline__ int swz(int q) { return q ^ ((q >> 4) & 7); }

__global__
__attribute__((amdgpu_flat_work_group_size(kThreads, kThreads),
               amdgpu_waves_per_eu(4, 4)))
void k_fused(
    const float* __restrict__ x, const float* g, const float* r,
    const float* mhp, const float* mbp, const float* mlp,
    float* __restrict__ out) {
  __shared__ float4 tbuf[8][256];              // 32 KB: 4 KB per wave
  __shared__ double s1[kThreads], s2[kThreads];  // 8 KB scan buffer

  const int t = threadIdx.x;
  const int l = t & 63;            // lane
  const int wave = t >> 6;
  const size_t rowoff = (size_t)blockIdx.x * kT;

  float b0, b1, b2, a1, a2;
  coeffs_f32(g, r, mhp, mbp, mlp, b0, b1, b2, a1, a2);
  float na1 = -a1, na2 = -a2;

  const int dl = (l >> 2) & 3;     // local slice when this lane is active
  const int m = l & 3;
  const int actgrp = l >> 4;       // round in which this lane reads/writes
  float4* wb = &tbuf[wave][0];

  // ---- stage in: coalesced global -> per-lane chunks (4 rounds) ----------
  const float4* xv = (const float4*)(x + rowoff) + (size_t)wave * 1024;
  float4 c[16];
#pragma unroll
  for (int j = 0; j < 4; ++j) {
    float4 v0 = xv[(4 * j + 0) * 64 + l];
    float4 v1 = xv[(4 * j + 1) * 64 + l];
    float4 v2 = xv[(4 * j + 2) * 64 + l];
    float4 v3 = xv[(4 * j + 3) * 64 + l];
    if (j) LGKM0();                // prior round's reads done before overwrite
    wb[swz(0 * 64 + l)] = v0;
    wb[swz(1 * 64 + l)] = v1;
    wb[swz(2 * 64 + l)] = v2;
    wb[swz(3 * 64 + l)] = v3;
    LGKM0();                       // writes visible before cross-lane reads
    if (actgrp == j) {
#pragma unroll
      for (int k = 0; k < 16; ++k) c[k] = wb[swz(dl * 64 + 16 * m + k)];
    }
  }

  // ---- pass 1: zero-init chunk final state d_t ---------------------------
  float z1 = 0.f, z2 = 0.f;
#pragma unroll
  for (int i = 0; i < 16; ++i) {
    float y;
    IIR_STEP(c[i].x, y); IIR_STEP(c[i].y, y);
    IIR_STEP(c[i].z, y); IIR_STEP(c[i].w, y);
  }

  // ---- scan: f64 LDS Kogge-Stone over 512 chunks, P = M^64 ---------------
  double w00 = -(double)a1, w01 = 1.0, w10 = -(double)a2, w11 = 0.0;
#pragma unroll
  for (int i = 0; i < 6; ++i) MAT_SQ(w00, w01, w10, w11);  // P = M^64

  double A0 = (double)z1, A1 = (double)z2;
  for (int o = 1; o < kThreads; o <<= 1) {  // 9 steps
    s1[t] = A0; s2[t] = A1;
    __syncthreads();
    double q0 = 0.0, q1 = 0.0;
    if (t >= o) { q0 = s1[t - o]; q1 = s2[t - o]; }
    __syncthreads();
    A0 += w00 * q0 + w01 * q1;
    A1 += w10 * q0 + w11 * q1;
    MAT_SQ(w00, w01, w10, w11);
  }
  s1[t] = A0; s2[t] = A1;
  __syncthreads();
  double e0 = 0.0, e1 = 0.0;
  if (t > 0) { e0 = s1[t - 1]; e1 = s2[t - 1]; }  // entering state of chunk t

  // ---- pass 2: rerun chunk from true entering state ----------------------
  z1 = (float)e0; z2 = (float)e1;
#pragma unroll
  for (int i = 0; i < 16; ++i) {
    float4 o4;
    IIR_STEP(c[i].x, o4.x); IIR_STEP(c[i].y, o4.y);
    IIR_STEP(c[i].z, o4.z); IIR_STEP(c[i].w, o4.w);
    c[i] = o4;
  }

  // ---- stage out: per-lane chunks -> coalesced global (4 rounds) ---------
  float4* yv = (float4*)(out + rowoff) + (size_t)wave * 1024;
#pragma unroll
  for (int j = 0; j < 4; ++j) {
    if (j) LGKM0();                // prior round's slice reads done
    if (actgrp == j) {
#pragma unroll
      for (int k = 0; k < 16; ++k) wb[swz(dl * 64 + 16 * m + k)] = c[k];
    }
    LGKM0();                       // chunk writes visible before slice reads
    yv[(4 * j + 0) * 64 + l] = wb[swz(0 * 64 + l)];
    yv[(4 * j + 1) * 64 + l] = wb[swz(1 * 64 + l)];
    yv[(4 * j + 2) * 64 + l] = wb[swz(2 * 64 + l)];
    yv[(4 * j + 3) * 64 + l] = wb[swz(3 * 64 + l)];
  }
}

extern "C" void kernel_launch(void* const* d_in, const int* in_sizes, int n_in,
                              void* d_out, int out_size, void* d_ws,
                              size_t ws_size, hipStream_t stream) {
  const float* x   = (const float*)d_in[0];
  const float* g   = (const float*)d_in[1];
  const float* r   = (const float*)d_in[2];
  const float* mhp = (const float*)d_in[3];
  const float* mbp = (const float*)d_in[4];
  const float* mlp = (const float*)d_in[5];
  float* out = (float*)d_out;
  (void)d_ws; (void)ws_size;

  k_fused<<<512, kThreads, 0, stream>>>(x, g, r, mhp, mbp, mlp, out);
}

// Round 6
// 128.443 us; speedup vs baseline: 1.5655x; 1.5655x over previous
//
#include <hip/hip_runtime.h>
#include <math.h>

// Fused single-kernel DSVF biquad IIR (scipy lfilter DF2T), B=512, T=32768.
// One block per row: 512 threads (8 waves), chunk = 64 samples per thread.
// R6: eliminate the 64-VGPR c[16] array (R3/R4/R5 all spilled it to scratch
// whenever the backend's LDS-occupancy heuristic targeted 8 waves/EU ->
// 64-VGPR budget; FETCH/WRITE showed 2-3.4x phantom HBM traffic).
//   - pass1 is fused INTO the stage-in rounds: a lane's whole chunk arrives
//     in one round, is consumed immediately (float4 at a time), and dies.
//   - pass2 re-stages x from global (second read is L3-resident: x = 64 MB
//     << 256 MB L3), active lanes apply the IIR from the true entering
//     state quad-by-quad, write y back to the same LDS slots, wave stores
//     slices coalesced.
//   - per-thread state across the scan: ~10 scalars. No spillable array.
//   - LDS padded to 57 KB -> max 2 blocks/CU -> backend targets 4 waves/EU
//     (128-VGPR budget); 2 blocks/CU x 256 CU = all 512 blocks resident.
// Transpose geometry (verified R4/R5): wave segment = 4096 samples = 16
// slices of 64 quads; round j stages slices 4j..4j+3 into the 4 KB wave
// buffer; lane l's chunk = slice l>>2, quads 16*(l&3)+k; active round
// actgrp = l>>4. XOR swizzle q^((q>>4)&7) keeps banks <=2-way.
// Scan: f64 LDS Kogge-Stone over 512 chunks, P = M^64 (verified).
// HBM: x read ~once from HBM (+ L3 re-read), y written once.

namespace {
constexpr int kT = 32768;
constexpr int kThreads = 512;   // 8 waves, one block per row
}

__device__ inline void coeffs_f32(const float* g, const float* r,
                                  const float* mhp, const float* mbp,
                                  const float* mlp, float& b0, float& b1,
                                  float& b2, float& a1, float& a2) {
  float graw = g[0], rraw = r[0];
  float sig = 1.0f / (1.0f + expf(-graw));
  float gg = tanf(1.5707963267948966f * sig);            // tan(pi*sigmoid/2)
  float rr = (rraw > 20.0f) ? rraw : log1pf(expf(rraw)); // softplus
  float g2 = gg * gg;
  float m_hp = mhp[0], m_bp = mbp[0], m_lp = mlp[0];
  float B0 = g2 * m_lp + gg * m_bp + m_hp;
  float B1 = 2.0f * g2 * m_lp - 2.0f * m_hp;
  float B2 = g2 * m_lp - gg * m_bp + m_hp;
  float A0 = g2 + 2.0f * rr * gg + 1.0f;
  float A1 = 2.0f * g2 - 2.0f;
  float A2 = g2 - 2.0f * rr * gg + 1.0f;
  float inv = 1.0f / A0;
  b0 = B0 * inv; b1 = B1 * inv; b2 = B2 * inv;
  a1 = A1 * inv; a2 = A2 * inv;
}

#define IIR_STEP(xx, yy)                                         \
  do {                                                           \
    yy = fmaf(b0, xx, z1);                                       \
    z1 = fmaf(na1, yy, fmaf(b1, xx, z2));                        \
    z2 = fmaf(na2, yy, b2 * xx);                                 \
  } while (0)

#define MAT_SQ(w00, w01, w10, w11)                               \
  do {                                                           \
    double t00 = w00 * w00 + w01 * w10;                          \
    double t01 = w00 * w01 + w01 * w11;                          \
    double t10 = w10 * w00 + w11 * w10;                          \
    double t11 = w10 * w01 + w11 * w11;                          \
    w00 = t00; w01 = t01; w10 = t10; w11 = t11;                  \
  } while (0)

#define LGKM0() asm volatile("s_waitcnt lgkmcnt(0)" ::: "memory")

__device__ __forceinline__ int swz(int q) { return q ^ ((q >> 4) & 7); }

__global__ __launch_bounds__(kThreads) void k_fused(
    const float* __restrict__ x, const float* g, const float* r,
    const float* mhp, const float* mbp, const float* mlp,
    float* __restrict__ out) {
  // 4 KB used per wave; padded to 6 KB/wave (48 KB) so LDS total = 57,344 B
  // -> exactly 2 blocks/CU -> backend occupancy target 4 waves/EU.
  __shared__ float4 tbuf[8][384];
  __shared__ double s1[kThreads], s2[kThreads];  // 8 KB scan buffer

  const int t = threadIdx.x;
  const int l = t & 63;            // lane
  const int wave = t >> 6;
  const size_t rowoff = (size_t)blockIdx.x * kT;

  float b0, b1, b2, a1, a2;
  coeffs_f32(g, r, mhp, mbp, mlp, b0, b1, b2, a1, a2);
  float na1 = -a1, na2 = -a2;

  const int dl = (l >> 2) & 3;     // local slice index when lane is active
  const int m16 = (l & 3) << 4;    // quad offset within slice
  const int actgrp = l >> 4;       // round in which this lane computes
  float4* wb = &tbuf[wave][0];
  const float4* xv = (const float4*)(x + rowoff) + (size_t)wave * 1024;

  // ---- stage-in + pass1 fused: zero-init chunk final state ----------------
  float z1 = 0.f, z2 = 0.f;
#pragma unroll
  for (int j = 0; j < 4; ++j) {
    float4 v0 = xv[(4 * j + 0) * 64 + l];
    float4 v1 = xv[(4 * j + 1) * 64 + l];
    float4 v2 = xv[(4 * j + 2) * 64 + l];
    float4 v3 = xv[(4 * j + 3) * 64 + l];
    if (j) LGKM0();                // prior round's reads done before overwrite
    wb[swz(0 * 64 + l)] = v0;
    wb[swz(1 * 64 + l)] = v1;
    wb[swz(2 * 64 + l)] = v2;
    wb[swz(3 * 64 + l)] = v3;
    LGKM0();                       // writes visible before cross-lane reads
    if (actgrp == j) {             // active lanes run their whole chunk now
#pragma unroll
      for (int k = 0; k < 16; ++k) {
        float4 q = wb[swz(dl * 64 + m16 + k)];
        float y;
        IIR_STEP(q.x, y); IIR_STEP(q.y, y);
        IIR_STEP(q.z, y); IIR_STEP(q.w, y);
      }
    }
  }
  // every lane now holds d_t = (z1, z2): its chunk's zero-init final state

  // ---- scan: f64 LDS Kogge-Stone over 512 chunks, P = M^64 ---------------
  double w00 = -(double)a1, w01 = 1.0, w10 = -(double)a2, w11 = 0.0;
#pragma unroll
  for (int i = 0; i < 6; ++i) MAT_SQ(w00, w01, w10, w11);  // P = M^64

  double A0 = (double)z1, A1 = (double)z2;
  for (int o = 1; o < kThreads; o <<= 1) {  // 9 steps
    s1[t] = A0; s2[t] = A1;
    __syncthreads();
    double q0 = 0.0, q1 = 0.0;
    if (t >= o) { q0 = s1[t - o]; q1 = s2[t - o]; }
    __syncthreads();
    A0 += w00 * q0 + w01 * q1;
    A1 += w10 * q0 + w11 * q1;
    MAT_SQ(w00, w01, w10, w11);
  }
  s1[t] = A0; s2[t] = A1;
  __syncthreads();
  double e0 = 0.0, e1 = 0.0;
  if (t > 0) { e0 = s1[t - 1]; e1 = s2[t - 1]; }  // entering state of chunk t

  // ---- pass2: re-stage x (L3-warm), rerun chunk, store y coalesced -------
  z1 = (float)e0; z2 = (float)e1;
  float4* yv = (float4*)(out + rowoff) + (size_t)wave * 1024;
#pragma unroll
  for (int j = 0; j < 4; ++j) {
    float4 v0 = xv[(4 * j + 0) * 64 + l];
    float4 v1 = xv[(4 * j + 1) * 64 + l];
    float4 v2 = xv[(4 * j + 2) * 64 + l];
    float4 v3 = xv[(4 * j + 3) * 64 + l];
    if (j) LGKM0();                // prior round's slice reads done
    wb[swz(0 * 64 + l)] = v0;
    wb[swz(1 * 64 + l)] = v1;
    wb[swz(2 * 64 + l)] = v2;
    wb[swz(3 * 64 + l)] = v3;
    LGKM0();                       // x slices visible
    if (actgrp == j) {             // rerun chunk from true entering state
#pragma unroll
      for (int k = 0; k < 16; ++k) {
        int idx = swz(dl * 64 + m16 + k);
        float4 q = wb[idx];
        float4 o4;
        IIR_STEP(q.x, o4.x); IIR_STEP(q.y, o4.y);
        IIR_STEP(q.z, o4.z); IIR_STEP(q.w, o4.w);
        wb[idx] = o4;              // y back to the same slot
      }
    }
    LGKM0();                       // y writes visible before slice reads
    yv[(4 * j + 0) * 64 + l] = wb[swz(0 * 64 + l)];
    yv[(4 * j + 1) * 64 + l] = wb[swz(1 * 64 + l)];
    yv[(4 * j + 2) * 64 + l] = wb[swz(2 * 64 + l)];
    yv[(4 * j + 3) * 64 + l] = wb[swz(3 * 64 + l)];
  }
}

extern "C" void kernel_launch(void* const* d_in, const int* in_sizes, int n_in,
                              void* d_out, int out_size, void* d_ws,
                              size_t ws_size, hipStream_t stream) {
  const float* x   = (const float*)d_in[0];
  const float* g   = (const float*)d_in[1];
  const float* r   = (const float*)d_in[2];
  const float* mhp = (const float*)d_in[3];
  const float* mbp = (const float*)d_in[4];
  const float* mlp = (const float*)d_in[5];
  float* out = (float*)d_out;
  (void)d_ws; (void)ws_size;

  k_fused<<<512, kThreads, 0, stream>>>(x, g, r, mhp, mbp, mlp, out);
}